// Round 4
// baseline (1074.389 us; speedup 1.0000x reference)
//
#include <hip/hip_runtime.h>
#include <hip/hip_bf16.h>
#include <math.h>

#define SELU_ALPHA 1.6732632423543772f
#define SELU_SCALE 1.0507009873554805f

typedef __attribute__((ext_vector_type(8))) short bf16x8;
typedef __attribute__((ext_vector_type(4))) float f32x4;

__device__ __forceinline__ float selu_f(float x) {
    return x > 0.f ? SELU_SCALE * x : SELU_SCALE * SELU_ALPHA * (__expf(x) - 1.f);
}
__device__ __forceinline__ unsigned short f2bf(float f) {
    __hip_bfloat16 h = __float2bfloat16(f);
    return *(unsigned short*)&h;
}
__device__ __forceinline__ float bf2f(unsigned short u) {
    unsigned int x = ((unsigned int)u) << 16;
    float f; __builtin_memcpy(&f, &x, 4); return f;
}

constexpr int Bb = 256, Ll = 100, Hh = 1000, Ee = 100, Rr = 247, Tt = 15;
constexpr int KP_G = 1024;             // padded K for H-sized bf16 GEMMs
constexpr int KP_E = 128;              // padded K for E-sized (gi) GEMM
constexpr int NCP = 3072;              // packed gate cols: 64 groups x 48 (r16|z16|n16)
constexpr int OUTW = Rr + 1 + Ll + 1;  // 349

// map packed col n' -> (part, j).  g=n'/48, rem=n'%48, part=rem/16, c=rem%16, j=g*16+c
__device__ __forceinline__ void unpack_col(int np, int& part, int& j) {
    int g = np / 48, rem = np % 48;
    part = rem >> 4;
    j = g * 16 + (rem & 15);
}

// ================= one-pass online-softmax attention ========================
__global__ void attn_online(const float* __restrict__ mem, const float* __restrict__ Wb,
                            int Nmem, int chunk, float* __restrict__ part_ms,
                            float* __restrict__ part_ctx, int nch) {
    __shared__ float4 sWb[256];
    __shared__ float sred[2][8];
    int b = blockIdx.x, ch = blockIdx.y;
    int tid = threadIdx.x, lane = tid & 63, wv = tid >> 6;
    sWb[tid] = (tid < 250) ? ((const float4*)Wb)[tid] : (float4){0.f,0.f,0.f,0.f};
    __syncthreads();
    int l0 = ch * chunk, l1 = min(Nmem, l0 + chunk);
    float m = -1e30f, ssum = 0.f;
    float4 ctx = {0.f,0.f,0.f,0.f};
    const float* base = mem + (size_t)b * Nmem * 1000;
    float4 w = sWb[tid];
    int it = 0;
    for (int l = l0; l < l1; l += 2, ++it) {
        bool has1 = (l + 1 < l1);
        float4 v0 = {0,0,0,0}, v1 = {0,0,0,0};
        if (tid < 250) v0 = *(const float4*)(base + (size_t)l * 1000 + tid * 4);
        if (has1 && tid < 250) v1 = *(const float4*)(base + (size_t)(l+1) * 1000 + tid * 4);
        float p0 = v0.x*w.x + v0.y*w.y + v0.z*w.z + v0.w*w.w;
        float p1 = v1.x*w.x + v1.y*w.y + v1.z*w.z + v1.w*w.w;
        #pragma unroll
        for (int off = 32; off > 0; off >>= 1) {
            p0 += __shfl_down(p0, off);
            p1 += __shfl_down(p1, off);
        }
        int par = it & 1;
        if (lane == 0) { sred[par][wv*2] = p0; sred[par][wv*2+1] = p1; }
        __syncthreads();
        float s0 = sred[par][0] + sred[par][2] + sred[par][4] + sred[par][6];
        float s1 = has1 ? (sred[par][1] + sred[par][3] + sred[par][5] + sred[par][7]) : -1e30f;
        float mn = fmaxf(m, fmaxf(s0, s1));
        float sc = __expf(m - mn);
        float w0 = __expf(s0 - mn);
        float w1 = has1 ? __expf(s1 - mn) : 0.f;
        ssum = ssum * sc + w0 + w1;
        ctx.x = ctx.x*sc + w0*v0.x + w1*v1.x;
        ctx.y = ctx.y*sc + w0*v0.y + w1*v1.y;
        ctx.z = ctx.z*sc + w0*v0.z + w1*v1.z;
        ctx.w = ctx.w*sc + w0*v0.w + w1*v1.w;
        m = mn;
    }
    int pidx = b * nch + ch;
    if (tid == 0) { part_ms[pidx*2] = m; part_ms[pidx*2 + 1] = ssum; }
    if (tid < 250) *(float4*)(part_ctx + (size_t)pidx * 1000 + tid * 4) = ctx;
}

__global__ void attn_combine(const float* __restrict__ part_ms, const float* __restrict__ part_ctx,
                             float* __restrict__ ctx_out, int nch) {
    __shared__ float sm[4], ss[4];
    int b = blockIdx.x, tid = threadIdx.x;
    if (tid < nch) { sm[tid] = part_ms[(b*nch + tid)*2]; ss[tid] = part_ms[(b*nch + tid)*2 + 1]; }
    __syncthreads();
    float M = -1e30f;
    for (int c = 0; c < nch; ++c) M = fmaxf(M, sm[c]);
    float tot = 0.f;
    for (int c = 0; c < nch; ++c) tot += ss[c] * __expf(sm[c] - M);
    float inv = 1.f / tot;
    if (tid < 250) {
        float4 acc = {0,0,0,0};
        for (int c = 0; c < nch; ++c) {
            float wgt = __expf(sm[c] - M) * inv;
            float4 v = *(const float4*)(part_ctx + (size_t)(b*nch + c)*1000 + tid*4);
            acc.x += wgt*v.x; acc.y += wgt*v.y; acc.z += wgt*v.z; acc.w += wgt*v.w;
        }
        *(float4*)(ctx_out + (size_t)b*1000 + tid*4) = acc;
    }
}

// ================= small precompute kernels =================================
__global__ void xcxrc_kernel(const float* __restrict__ c, const float* __restrict__ rc,
                             const float* __restrict__ W_comb, const float* __restrict__ b_comb,
                             float* __restrict__ xc, float* __restrict__ xrc) {
    __shared__ float sc[1000];
    __shared__ float sr[1000];
    int b = blockIdx.x, tid = threadIdx.x;  // 128 threads
    for (int k = tid; k < Hh; k += 128) { sc[k] = c[(size_t)b*Hh+k]; sr[k] = rc[(size_t)b*Hh+k]; }
    __syncthreads();
    if (tid < Ee) {
        float a0 = 0.f, a1 = 0.f;
        for (int k = 0; k < Hh; ++k) {
            float w = W_comb[(size_t)(Ee + k)*Ee + tid];
            a0 += sc[k]*w; a1 += sr[k]*w;
        }
        xc [(size_t)b*Ee + tid] = a0 + b_comb[tid];
        xrc[(size_t)b*Ee + tid] = a1 + b_comb[tid];
    }
}

// x_allb[t*256+b][128] (bf16) = emb@W_comb_top + (t%3?xc:xrc), zero-padded
__global__ void xall_kernel(const float* __restrict__ emb, const float* __restrict__ W_comb,
                            const float* __restrict__ xc, const float* __restrict__ xrc,
                            unsigned short* __restrict__ x_allb) {
    __shared__ float se[100];
    int bt = blockIdx.x; int b = bt / Tt, t = bt % Tt;
    int tid = threadIdx.x;  // 128
    if (tid < Ee) se[tid] = emb[(size_t)(b*Tt + t)*Ee + tid];
    __syncthreads();
    float v = 0.f;
    if (tid < Ee) {
        float a = 0.f;
        for (int k = 0; k < Ee; ++k) a += se[k] * W_comb[(size_t)k*Ee + tid];
        const float* xs = (t % 3 == 0) ? xrc : xc;
        v = a + xs[(size_t)b*Ee + tid];
    }
    x_allb[((size_t)t*Bb + b)*KP_E + tid] = f2bf(v);
}

// transpose+convert: dst[n][k] (ld 1024) = bf16(src[(row0+k)*srcLd + n]), zero-padded
__global__ void transpose_cvt(const float* __restrict__ src, int srcLd, int kValid, int nValid,
                              int row0, unsigned short* __restrict__ dst, int nRows) {
    __shared__ float tile[32][33];
    int k0 = blockIdx.x * 32, n0 = blockIdx.y * 32;
    int tx = threadIdx.x, ty = threadIdx.y;  // 32 x 8
    for (int i = ty; i < 32; i += 8) {
        int k = k0 + i, n = n0 + tx;
        tile[i][tx] = (k < kValid && n < nValid) ? src[(size_t)(row0 + k)*srcLd + n] : 0.f;
    }
    __syncthreads();
    for (int i = ty; i < 32; i += 8) {
        int n = n0 + i, k = k0 + tx;
        if (n < nRows) dst[(size_t)n*KP_G + k] = f2bf(tile[tx][i]);
    }
}

// packed-gate transpose: dst[np][k] (ld dstLd) = bf16(src[k][part*1000+j]); src [kValid][3000]
__global__ void pack_gates_T(const float* __restrict__ src, int kValid,
                             unsigned short* __restrict__ dst, int dstLd) {
    __shared__ float tile[32][33];
    int k0 = blockIdx.x * 32, n0 = blockIdx.y * 32;
    int tx = threadIdx.x, ty = threadIdx.y;  // 32 x 8
    for (int i = ty; i < 32; i += 8) {
        int k = k0 + i, np = n0 + tx;
        int part, j; unpack_col(np, part, j);
        tile[i][tx] = (k < kValid && j < Hh) ? src[(size_t)k*3000 + part*1000 + j] : 0.f;
    }
    __syncthreads();
    for (int i = ty; i < 32; i += 8) {
        int np = n0 + i, k = k0 + tx;
        dst[(size_t)np*dstLd + k] = f2bf(tile[tx][i]);
    }
}

__global__ void fill_eos_row(const float* __restrict__ W_eos, unsigned short* __restrict__ Whead) {
    int k = blockIdx.x*256 + threadIdx.x;
    if (k < KP_G) Whead[(size_t)247*KP_G + k] = f2bf(k < Hh ? W_eos[k] : 0.f);
}

__global__ void pack_biases(const float* __restrict__ b_hh, const float* __restrict__ b_ih,
                            const float* __restrict__ b_pred, const float* __restrict__ b_eos,
                            float* __restrict__ bhhp, float* __restrict__ bihp,
                            float* __restrict__ bias_pe) {
    int i = blockIdx.x*256 + threadIdx.x;
    if (i < NCP) {
        int part, j; unpack_col(i, part, j);
        bhhp[i] = (j < Hh) ? b_hh[part*1000 + j] : 0.f;
        bihp[i] = (j < Hh) ? b_ih[part*1000 + j] : 0.f;
    }
    if (i < 256) bias_pe[i] = (i < 247) ? b_pred[i] : (i == 247 ? b_eos[0] : 0.f);
}

__global__ void cvt_h0(const float* __restrict__ h0, unsigned short* __restrict__ h0b,
                       float* __restrict__ h0f) {
    int i = blockIdx.x*256 + threadIdx.x;  // 256*1024
    int b = i >> 10, j = i & 1023;
    float v = (j < Hh) ? h0[(size_t)b*Hh + j] : 0.f;
    h0b[i] = f2bf(v);
    h0f[i] = v;
}

// ================= bf16 MFMA GEMM: C = act(A) @ B^T + bias ===================
// Bt[n][k], k padded to KTOT. AMODE 0: A bf16 [M][KTOT]. AMODE 1: A fp32 [M][1000] selu.
// AMODE 2: A bf16 [M][KTOT], selu.
template<int AMODE, int KTOT>
__launch_bounds__(256)
__global__ void gemm_bf16(const void* __restrict__ Aptr, const unsigned short* __restrict__ Bt,
                          const float* __restrict__ bias, float* __restrict__ C, int ldc) {
    constexpr int BM = 64, BN = 128, BK = 64, KP = 72;
    __shared__ unsigned short As[BM * KP];
    __shared__ unsigned short Bs[BN * KP];
    int tid = threadIdx.x;
    int m0 = blockIdx.y * BM, n0 = blockIdx.x * BN;
    int lane = tid & 63, wid = tid >> 6;
    int wm = wid >> 1, wn = wid & 1;
    f32x4 acc[2][4];
    #pragma unroll
    for (int i = 0; i < 2; i++)
        #pragma unroll
        for (int j = 0; j < 4; j++) acc[i][j] = (f32x4){0.f, 0.f, 0.f, 0.f};

    for (int k0 = 0; k0 < KTOT; k0 += BK) {
        #pragma unroll
        for (int e = 0; e < 2; ++e) {
            int idx = tid + e*256;
            int row = idx >> 3, kc = idx & 7;
            int k = k0 + kc*8;
            int rg = m0 + row;
            bf16x8 v;
            if (AMODE == 1) {
                if (k < Hh) {
                    const float4* p = (const float4*)((const float*)Aptr + (size_t)rg*Hh + k);
                    float4 x = p[0], y = p[1];
                    v[0]=(short)f2bf(selu_f(x.x)); v[1]=(short)f2bf(selu_f(x.y));
                    v[2]=(short)f2bf(selu_f(x.z)); v[3]=(short)f2bf(selu_f(x.w));
                    v[4]=(short)f2bf(selu_f(y.x)); v[5]=(short)f2bf(selu_f(y.y));
                    v[6]=(short)f2bf(selu_f(y.z)); v[7]=(short)f2bf(selu_f(y.w));
                } else {
                    #pragma unroll
                    for (int j = 0; j < 8; j++) v[j] = 0;
                }
            } else {
                v = *(const bf16x8*)((const unsigned short*)Aptr + (size_t)rg*KTOT + k);
                if (AMODE == 2) {
                    #pragma unroll
                    for (int j = 0; j < 8; j++)
                        v[j] = (short)f2bf(selu_f(bf2f((unsigned short)v[j])));
                }
            }
            *(bf16x8*)(&As[row*KP + kc*8]) = v;
        }
        #pragma unroll
        for (int e = 0; e < 4; ++e) {
            int idx = tid + e*256;
            int row = idx >> 3, kc = idx & 7;
            bf16x8 v = *(const bf16x8*)(Bt + (size_t)(n0 + row)*KTOT + k0 + kc*8);
            *(bf16x8*)(&Bs[row*KP + kc*8]) = v;
        }
        __syncthreads();
        #pragma unroll
        for (int kk = 0; kk < 2; ++kk) {
            bf16x8 af[2], bfr[4];
            #pragma unroll
            for (int mi = 0; mi < 2; mi++)
                af[mi] = *(const bf16x8*)(&As[(wm*32 + mi*16 + (lane & 15))*KP + kk*32 + (lane >> 4)*8]);
            #pragma unroll
            for (int ni = 0; ni < 4; ni++)
                bfr[ni] = *(const bf16x8*)(&Bs[(wn*64 + ni*16 + (lane & 15))*KP + kk*32 + (lane >> 4)*8]);
            #pragma unroll
            for (int mi = 0; mi < 2; mi++)
                #pragma unroll
                for (int ni = 0; ni < 4; ni++)
                    acc[mi][ni] = __builtin_amdgcn_mfma_f32_16x16x32_bf16(af[mi], bfr[ni], acc[mi][ni], 0, 0, 0);
        }
        __syncthreads();
    }
    int cr = (lane >> 4) * 4, cc = lane & 15;
    #pragma unroll
    for (int mi = 0; mi < 2; mi++) {
        #pragma unroll
        for (int ni = 0; ni < 4; ni++) {
            int col = n0 + wn*64 + ni*16 + cc;
            float bv = bias ? bias[col] : 0.f;
            #pragma unroll
            for (int r = 0; r < 4; r++) {
                int row = m0 + wm*32 + mi*16 + cr + r;
                C[(size_t)row*ldc + col] = acc[mi][ni][r] + bv;
            }
        }
    }
}

// ================= persistent GRU: all 15 steps in one dispatch ==============
// grid (64, 4) = 256 blocks (1/CU): blockIdx.x = gate-group g (16 j's x 3 gates),
// blockIdx.y = m-tile (64 batch rows). W-slice LDS-resident across steps; h fp32
// lives in registers (this block is both producer and consumer of its (row,j) set).
__launch_bounds__(256, 1)
__global__ void gru_persist(const unsigned short* __restrict__ h0b,
                            const float* __restrict__ h0f,
                            const unsigned short* __restrict__ Wp,
                            const float* __restrict__ bhhp,
                            const float* __restrict__ gi_all,
                            unsigned short* __restrict__ hb_all,
                            int* __restrict__ counters) {
    constexpr int KP = 1032;  // +8 pad: row stride 2064B -> 2-way bank alias (free)
    __shared__ unsigned short Bs[48 * KP];
    int tid = threadIdx.x, lane = tid & 63, wv = tid >> 6;
    int g = blockIdx.x, m0 = blockIdx.y * 64;
    int c = lane & 15, koff = (lane >> 4) * 8;

    // ---- load W slice once: 48 packed rows x 1024 k ----
    for (int i = tid; i < 48*128; i += 256) {
        int row = i >> 7, kc = i & 127;
        *(bf16x8*)(&Bs[row*KP + kc*8]) = *(const bf16x8*)(Wp + (size_t)(g*48 + row)*KP_G + kc*8);
    }
    float br = bhhp[g*48 + c], bz = bhhp[g*48 + 16 + c], bn_ = bhhp[g*48 + 32 + c];
    int rbase = wv*16 + ((lane >> 4) << 2);   // C-frag rows
    int j = g*16 + c;
    float hp[4];
    #pragma unroll
    for (int r = 0; r < 4; r++) hp[r] = h0f[(size_t)(m0 + rbase + r)*KP_G + j];
    __syncthreads();

    int arow = m0 + wv*16 + (lane & 15);      // A-frag row
    for (int t = 0; t < Tt; ++t) {
        const unsigned short* A = t ? hb_all + (size_t)(t-1)*Bb*KP_G : h0b;
        const unsigned short* ap = A + (size_t)arow*KP_G + koff;
        f32x4 acc[3];
        #pragma unroll
        for (int f = 0; f < 3; f++) acc[f] = (f32x4){0.f,0.f,0.f,0.f};
        int bb0 = (0*16 + c)*KP + koff;
        int bb1 = (1*16 + c)*KP + koff;
        int bb2 = (2*16 + c)*KP + koff;
        #pragma unroll 8
        for (int ks = 0; ks < 32; ++ks) {
            bf16x8 af = *(const bf16x8*)(ap + ks*32);
            bf16x8 b0 = *(const bf16x8*)(&Bs[bb0 + ks*32]);
            bf16x8 b1 = *(const bf16x8*)(&Bs[bb1 + ks*32]);
            bf16x8 b2 = *(const bf16x8*)(&Bs[bb2 + ks*32]);
            acc[0] = __builtin_amdgcn_mfma_f32_16x16x32_bf16(af, b0, acc[0], 0, 0, 0);
            acc[1] = __builtin_amdgcn_mfma_f32_16x16x32_bf16(af, b1, acc[1], 0, 0, 0);
            acc[2] = __builtin_amdgcn_mfma_f32_16x16x32_bf16(af, b2, acc[2], 0, 0, 0);
        }
        const float* gi = gi_all + (size_t)t*Bb*NCP;
        unsigned short* hbt = hb_all + (size_t)t*Bb*KP_G;
        #pragma unroll
        for (int r = 0; r < 4; r++) {
            int row = m0 + rbase + r;
            const float* gr = gi + (size_t)row*NCP + g*48;
            float rr = 1.f/(1.f + __expf(-(gr[c]      + acc[0][r] + br)));
            float zz = 1.f/(1.f + __expf(-(gr[16 + c] + acc[1][r] + bz)));
            float nn = tanhf(gr[32 + c] + rr*(acc[2][r] + bn_));
            float h = (1.f - zz)*nn + zz*hp[r];
            hp[r] = h;
            hbt[(size_t)row*KP_G + j] = f2bf(h);
        }
        if (t < Tt - 1) {
            // release h writes, then grid barrier on counter[t]
            __threadfence();
            __syncthreads();
            if (tid == 0) {
                atomicAdd(&counters[t], 1);
                while (__hip_atomic_load(&counters[t], __ATOMIC_ACQUIRE,
                                         __HIP_MEMORY_SCOPE_AGENT) < 256) {
                    __builtin_amdgcn_s_sleep(1);
                }
            }
            __syncthreads();
            __threadfence();
        }
    }
}

// ================= per-(t,b) outputs ========================================
__global__ void output_kernel(const float* __restrict__ pe, const float* __restrict__ fu,
                              const float* __restrict__ encf, const float* __restrict__ b_fuse,
                              const float* __restrict__ W_copy, const float* __restrict__ b_copy,
                              float* __restrict__ out) {
    __shared__ float sf[100];
    __shared__ float swc[100];
    __shared__ float scp[101];
    __shared__ float spred[248];
    __shared__ float sred[256];
    int row = blockIdx.x;               // t*256 + b
    int b = row & 255;
    int tid = threadIdx.x, lane = tid & 63, wave = tid >> 6;
    if (tid < 100) { sf[tid] = fu[(size_t)row*128 + tid] + b_fuse[tid]; swc[tid] = W_copy[tid]; }
    if (tid < 248) spred[tid] = pe[(size_t)row*256 + tid];
    __syncthreads();
    if (tid == 0) scp[100] = spred[247];
    const float* efb = encf + (size_t)b*Ll*128;
    for (int l = wave; l < Ll; l += 4) {
        const float* ef = efb + (size_t)l*128;
        float p = selu_f(sf[lane] + ef[lane]) * swc[lane];
        if (lane < 36) p += selu_f(sf[lane+64] + ef[lane+64]) * swc[lane+64];
        for (int off = 32; off > 0; off >>= 1) p += __shfl_down(p, off);
        if (lane == 0) scp[l] = p + b_copy[0];
    }
    __syncthreads();
    float* ob = out + (size_t)row*OUTW;
    float m = (tid < 248) ? spred[tid] : -1e30f;
    sred[tid] = m; __syncthreads();
    for (int s = 128; s > 0; s >>= 1) { if (tid < s) sred[tid] = fmaxf(sred[tid], sred[tid+s]); __syncthreads(); }
    m = sred[0]; __syncthreads();
    float ps = (tid < 248) ? expf(spred[tid] - m) : 0.f;
    sred[tid] = ps; __syncthreads();
    for (int s = 128; s > 0; s >>= 1) { if (tid < s) sred[tid] += sred[tid+s]; __syncthreads(); }
    float lse = m + logf(sred[0]);
    __syncthreads();
    if (tid < 248) ob[tid] = spred[tid] - lse;
    m = (tid < 101) ? scp[tid] : -1e30f;
    sred[tid] = m; __syncthreads();
    for (int s = 128; s > 0; s >>= 1) { if (tid < s) sred[tid] = fmaxf(sred[tid], sred[tid+s]); __syncthreads(); }
    m = sred[0]; __syncthreads();
    ps = (tid < 101) ? expf(scp[tid] - m) : 0.f;
    sred[tid] = ps; __syncthreads();
    for (int s = 128; s > 0; s >>= 1) { if (tid < s) sred[tid] += sred[tid+s]; __syncthreads(); }
    lse = m + logf(sred[0]);
    __syncthreads();
    if (tid < 101) ob[248 + tid] = scp[tid] - lse;
}

// ============================================================================
extern "C" void kernel_launch(void* const* d_in, const int* in_sizes, int n_in,
                              void* d_out, int out_size, void* d_ws, size_t ws_size,
                              hipStream_t stream) {
    const float* emb    = (const float*)d_in[0];
    const float* enc    = (const float*)d_in[1];
    const float* conv   = (const float*)d_in[2];
    const float* h0     = (const float*)d_in[3];
    const float* W_attn = (const float*)d_in[4];
    const float* W_comb = (const float*)d_in[6];
    const float* b_comb = (const float*)d_in[7];
    const float* W_ih   = (const float*)d_in[8];
    const float* W_hh   = (const float*)d_in[9];
    const float* b_ih   = (const float*)d_in[10];
    const float* b_hh   = (const float*)d_in[11];
    const float* W_eos  = (const float*)d_in[12];
    const float* b_eos  = (const float*)d_in[13];
    const float* W_pred = (const float*)d_in[14];
    const float* b_pred = (const float*)d_in[15];
    const float* W_fuse = (const float*)d_in[16];
    const float* b_fuse = (const float*)d_in[17];
    const float* W_copy = (const float*)d_in[18];
    const float* b_copy = (const float*)d_in[19];
    float* out = (float*)d_out;

    char* p = (char*)d_ws;
    auto alloc = [&](size_t bytes) -> void* {
        void* r = (void*)p; p += (bytes + 255) & ~(size_t)255; return r;
    };
    float* pm_enc   = (float*)alloc((size_t)Bb*2*2*4);
    float* pm_conv  = (float*)alloc((size_t)Bb*4*2*4);
    float* pc_enc   = (float*)alloc((size_t)Bb*2*1000*4);
    float* pc_conv  = (float*)alloc((size_t)Bb*4*1000*4);
    float* c_buf  = (float*)alloc((size_t)Bb*Hh*4);
    float* rc_buf = (float*)alloc((size_t)Bb*Hh*4);
    float* xc     = (float*)alloc((size_t)Bb*Ee*4);
    float* xrc    = (float*)alloc((size_t)Bb*Ee*4);
    unsigned short* x_allb = (unsigned short*)alloc((size_t)Tt*Bb*KP_E*2);
    float* gi_all = (float*)alloc((size_t)Tt*Bb*NCP*4);
    float* encf   = (float*)alloc((size_t)Bb*Ll*128*4);
    unsigned short* Wp    = (unsigned short*)alloc((size_t)NCP*KP_G*2);
    unsigned short* Wihpb = (unsigned short*)alloc((size_t)NCP*KP_E*2);
    unsigned short* Whead = (unsigned short*)alloc((size_t)256*KP_G*2);
    unsigned short* Wft   = (unsigned short*)alloc((size_t)128*KP_G*2);
    unsigned short* Wfb   = (unsigned short*)alloc((size_t)128*KP_G*2);
    float* bhhp    = (float*)alloc(NCP*4);
    float* bihp    = (float*)alloc(NCP*4);
    float* bias_pe = (float*)alloc(256*4);
    float* h0f = (float*)alloc((size_t)Bb*KP_G*4);
    unsigned short* h0b    = (unsigned short*)alloc((size_t)Bb*KP_G*2);
    unsigned short* hb_all = (unsigned short*)alloc((size_t)Tt*Bb*KP_G*2);
    float* pe = (float*)alloc((size_t)Tt*Bb*256*4);
    float* fu = (float*)alloc((size_t)Tt*Bb*128*4);
    int*   counters = (int*)alloc(16*4);

    hipMemsetAsync(counters, 0, 16*4, stream);

    // ---- attention (time-invariant; one pass, online softmax) ----
    attn_online<<<dim3(Bb, 2), 256, 0, stream>>>(enc,  W_attn + Hh, Ll, 50, pm_enc,  pc_enc,  2);
    attn_online<<<dim3(Bb, 4), 256, 0, stream>>>(conv, W_attn + Hh, Rr, 62, pm_conv, pc_conv, 4);
    attn_combine<<<Bb, 256, 0, stream>>>(pm_enc,  pc_enc,  c_buf,  2);
    attn_combine<<<Bb, 256, 0, stream>>>(pm_conv, pc_conv, rc_buf, 4);
    xcxrc_kernel<<<Bb, 128, 0, stream>>>(c_buf, rc_buf, W_comb, b_comb, xc, xrc);
    xall_kernel<<<Bb*Tt, 128, 0, stream>>>(emb, W_comb, xc, xrc, x_allb);

    // ---- weight packing ----
    pack_gates_T<<<dim3(32, 96), dim3(32, 8), 0, stream>>>(W_hh, Hh, Wp,    KP_G);
    pack_gates_T<<<dim3(4,  96), dim3(32, 8), 0, stream>>>(W_ih, Ee, Wihpb, KP_E);
    transpose_cvt<<<dim3(32, 8), dim3(32, 8), 0, stream>>>(W_pred, 247, Hh, 247, 0,    Whead, 256);
    fill_eos_row<<<4, 256, 0, stream>>>(W_eos, Whead);
    transpose_cvt<<<dim3(32, 4), dim3(32, 8), 0, stream>>>(W_fuse, 100, Hh, 100, 0,    Wft, 128);
    transpose_cvt<<<dim3(32, 4), dim3(32, 8), 0, stream>>>(W_fuse, 100, Hh, 100, 1000, Wfb, 128);
    pack_biases<<<12, 256, 0, stream>>>(b_hh, b_ih, b_pred, b_eos, bhhp, bihp, bias_pe);
    cvt_h0<<<Bb*KP_G/256, 256, 0, stream>>>(h0, h0b, h0f);

    // ---- batched precompute GEMMs ----
    gemm_bf16<0,KP_E><<<dim3(NCP/128, Tt*Bb/64), 256, 0, stream>>>(x_allb, Wihpb, bihp, gi_all, NCP);
    gemm_bf16<1,KP_G><<<dim3(1, (Bb*Ll)/64), 256, 0, stream>>>(enc, Wfb, nullptr, encf, 128);

    // ---- serial GRU: ONE persistent dispatch over all 15 steps ----
    gru_persist<<<dim3(64, 4), 256, 0, stream>>>(h0b, h0f, Wp, bhhp, gi_all, hb_all, counters);

    // ---- batched heads over all (t,b) ----
    gemm_bf16<0,KP_G><<<dim3(2, Tt*Bb/64), 256, 0, stream>>>(hb_all, Whead, bias_pe, pe, 256);
    gemm_bf16<2,KP_G><<<dim3(1, Tt*Bb/64), 256, 0, stream>>>(hb_all, Wft, nullptr, fu, 128);
    output_kernel<<<Tt*Bb, 256, 0, stream>>>(pe, fu, encf, b_fuse, W_copy, b_copy, out);
}

// Round 5
// 537.868 us; speedup vs baseline: 1.9975x; 1.9975x over previous
//
#include <hip/hip_runtime.h>
#include <hip/hip_bf16.h>
#include <math.h>

#define SELU_ALPHA 1.6732632423543772f
#define SELU_SCALE 1.0507009873554805f

typedef __attribute__((ext_vector_type(8))) short bf16x8;
typedef __attribute__((ext_vector_type(4))) float f32x4;

__device__ __forceinline__ float selu_f(float x) {
    return x > 0.f ? SELU_SCALE * x : SELU_SCALE * SELU_ALPHA * (__expf(x) - 1.f);
}
__device__ __forceinline__ unsigned short f2bf(float f) {
    __hip_bfloat16 h = __float2bfloat16(f);
    return *(unsigned short*)&h;
}
__device__ __forceinline__ float bf2f(unsigned short u) {
    unsigned int x = ((unsigned int)u) << 16;
    float f; __builtin_memcpy(&f, &x, 4); return f;
}

constexpr int Bb = 256, Ll = 100, Hh = 1000, Ee = 100, Rr = 247, Tt = 15;
constexpr int KP_G = 1024;             // padded K for H-sized bf16 GEMMs
constexpr int KP_E = 128;              // padded K for E-sized (gi) GEMM
constexpr int NCP = 3072;              // packed gate cols: 64 groups x 48 (r16|z16|n16)
constexpr int OUTW = Rr + 1 + Ll + 1;  // 349

// map packed col n' -> (part, j).  g=n'/48, rem=n'%48, part=rem/16, c=rem%16, j=g*16+c
__device__ __forceinline__ void unpack_col(int np, int& part, int& j) {
    int g = np / 48, rem = np % 48;
    part = rem >> 4;
    j = g * 16 + (rem & 15);
}

// ================= one-pass online-softmax attention ========================
__global__ void attn_online(const float* __restrict__ mem, const float* __restrict__ Wb,
                            int Nmem, int chunk, float* __restrict__ part_ms,
                            float* __restrict__ part_ctx, int nch) {
    __shared__ float4 sWb[256];
    __shared__ float sred[2][8];
    int b = blockIdx.x, ch = blockIdx.y;
    int tid = threadIdx.x, lane = tid & 63, wv = tid >> 6;
    sWb[tid] = (tid < 250) ? ((const float4*)Wb)[tid] : (float4){0.f,0.f,0.f,0.f};
    __syncthreads();
    int l0 = ch * chunk, l1 = min(Nmem, l0 + chunk);
    float m = -1e30f, ssum = 0.f;
    float4 ctx = {0.f,0.f,0.f,0.f};
    const float* base = mem + (size_t)b * Nmem * 1000;
    float4 w = sWb[tid];
    int it = 0;
    for (int l = l0; l < l1; l += 2, ++it) {
        bool has1 = (l + 1 < l1);
        float4 v0 = {0,0,0,0}, v1 = {0,0,0,0};
        if (tid < 250) v0 = *(const float4*)(base + (size_t)l * 1000 + tid * 4);
        if (has1 && tid < 250) v1 = *(const float4*)(base + (size_t)(l+1) * 1000 + tid * 4);
        float p0 = v0.x*w.x + v0.y*w.y + v0.z*w.z + v0.w*w.w;
        float p1 = v1.x*w.x + v1.y*w.y + v1.z*w.z + v1.w*w.w;
        #pragma unroll
        for (int off = 32; off > 0; off >>= 1) {
            p0 += __shfl_down(p0, off);
            p1 += __shfl_down(p1, off);
        }
        int par = it & 1;
        if (lane == 0) { sred[par][wv*2] = p0; sred[par][wv*2+1] = p1; }
        __syncthreads();
        float s0 = sred[par][0] + sred[par][2] + sred[par][4] + sred[par][6];
        float s1 = has1 ? (sred[par][1] + sred[par][3] + sred[par][5] + sred[par][7]) : -1e30f;
        float mn = fmaxf(m, fmaxf(s0, s1));
        float sc = __expf(m - mn);
        float w0 = __expf(s0 - mn);
        float w1 = has1 ? __expf(s1 - mn) : 0.f;
        ssum = ssum * sc + w0 + w1;
        ctx.x = ctx.x*sc + w0*v0.x + w1*v1.x;
        ctx.y = ctx.y*sc + w0*v0.y + w1*v1.y;
        ctx.z = ctx.z*sc + w0*v0.z + w1*v1.z;
        ctx.w = ctx.w*sc + w0*v0.w + w1*v1.w;
        m = mn;
    }
    int pidx = b * nch + ch;
    if (tid == 0) { part_ms[pidx*2] = m; part_ms[pidx*2 + 1] = ssum; }
    if (tid < 250) *(float4*)(part_ctx + (size_t)pidx * 1000 + tid * 4) = ctx;
}

__global__ void attn_combine(const float* __restrict__ part_ms, const float* __restrict__ part_ctx,
                             float* __restrict__ ctx_out, int nch) {
    __shared__ float sm[4], ss[4];
    int b = blockIdx.x, tid = threadIdx.x;
    if (tid < nch) { sm[tid] = part_ms[(b*nch + tid)*2]; ss[tid] = part_ms[(b*nch + tid)*2 + 1]; }
    __syncthreads();
    float M = -1e30f;
    for (int c = 0; c < nch; ++c) M = fmaxf(M, sm[c]);
    float tot = 0.f;
    for (int c = 0; c < nch; ++c) tot += ss[c] * __expf(sm[c] - M);
    float inv = 1.f / tot;
    if (tid < 250) {
        float4 acc = {0,0,0,0};
        for (int c = 0; c < nch; ++c) {
            float wgt = __expf(sm[c] - M) * inv;
            float4 v = *(const float4*)(part_ctx + (size_t)(b*nch + c)*1000 + tid*4);
            acc.x += wgt*v.x; acc.y += wgt*v.y; acc.z += wgt*v.z; acc.w += wgt*v.w;
        }
        *(float4*)(ctx_out + (size_t)b*1000 + tid*4) = acc;
    }
}

// ================= small precompute kernels =================================
__global__ void xcxrc_kernel(const float* __restrict__ c, const float* __restrict__ rc,
                             const float* __restrict__ W_comb, const float* __restrict__ b_comb,
                             float* __restrict__ xc, float* __restrict__ xrc) {
    __shared__ float sc[1000];
    __shared__ float sr[1000];
    int b = blockIdx.x, tid = threadIdx.x;  // 128 threads
    for (int k = tid; k < Hh; k += 128) { sc[k] = c[(size_t)b*Hh+k]; sr[k] = rc[(size_t)b*Hh+k]; }
    __syncthreads();
    if (tid < Ee) {
        float a0 = 0.f, a1 = 0.f;
        for (int k = 0; k < Hh; ++k) {
            float w = W_comb[(size_t)(Ee + k)*Ee + tid];
            a0 += sc[k]*w; a1 += sr[k]*w;
        }
        xc [(size_t)b*Ee + tid] = a0 + b_comb[tid];
        xrc[(size_t)b*Ee + tid] = a1 + b_comb[tid];
    }
}

// x_allb[t*256+b][128] (bf16) = emb@W_comb_top + (t%3?xc:xrc), zero-padded
__global__ void xall_kernel(const float* __restrict__ emb, const float* __restrict__ W_comb,
                            const float* __restrict__ xc, const float* __restrict__ xrc,
                            unsigned short* __restrict__ x_allb) {
    __shared__ float se[100];
    int bt = blockIdx.x; int b = bt / Tt, t = bt % Tt;
    int tid = threadIdx.x;  // 128
    if (tid < Ee) se[tid] = emb[(size_t)(b*Tt + t)*Ee + tid];
    __syncthreads();
    float v = 0.f;
    if (tid < Ee) {
        float a = 0.f;
        for (int k = 0; k < Ee; ++k) a += se[k] * W_comb[(size_t)k*Ee + tid];
        const float* xs = (t % 3 == 0) ? xrc : xc;
        v = a + xs[(size_t)b*Ee + tid];
    }
    x_allb[((size_t)t*Bb + b)*KP_E + tid] = f2bf(v);
}

// transpose+convert: dst[n][k] (ld 1024) = bf16(src[(row0+k)*srcLd + n]), zero-padded
__global__ void transpose_cvt(const float* __restrict__ src, int srcLd, int kValid, int nValid,
                              int row0, unsigned short* __restrict__ dst, int nRows) {
    __shared__ float tile[32][33];
    int k0 = blockIdx.x * 32, n0 = blockIdx.y * 32;
    int tx = threadIdx.x, ty = threadIdx.y;  // 32 x 8
    for (int i = ty; i < 32; i += 8) {
        int k = k0 + i, n = n0 + tx;
        tile[i][tx] = (k < kValid && n < nValid) ? src[(size_t)(row0 + k)*srcLd + n] : 0.f;
    }
    __syncthreads();
    for (int i = ty; i < 32; i += 8) {
        int n = n0 + i, k = k0 + tx;
        if (n < nRows) dst[(size_t)n*KP_G + k] = f2bf(tile[tx][i]);
    }
}

// W_fuse top/bot halves in one launch (z=0 -> top rows 0..999 -> dstA; z=1 -> rows 1000.. -> dstB)
__global__ void transpose_cvt_fuse(const float* __restrict__ W_fuse,
                                   unsigned short* __restrict__ Wft,
                                   unsigned short* __restrict__ Wfb) {
    __shared__ float tile[32][33];
    int k0 = blockIdx.x * 32, n0 = blockIdx.y * 32;
    int row0 = blockIdx.z ? 1000 : 0;
    unsigned short* dst = blockIdx.z ? Wfb : Wft;
    int tx = threadIdx.x, ty = threadIdx.y;  // 32 x 8
    for (int i = ty; i < 32; i += 8) {
        int k = k0 + i, n = n0 + tx;
        tile[i][tx] = (k < Hh && n < 100) ? W_fuse[(size_t)(row0 + k)*100 + n] : 0.f;
    }
    __syncthreads();
    for (int i = ty; i < 32; i += 8) {
        int n = n0 + i, k = k0 + tx;
        dst[(size_t)n*KP_G + k] = f2bf(tile[tx][i]);
    }
}

// packed-gate transpose: dst[np][k] (ld dstLd) = bf16(src[k][part*1000+j]); src [kValid][3000]
__global__ void pack_gates_T(const float* __restrict__ src, int kValid,
                             unsigned short* __restrict__ dst, int dstLd) {
    __shared__ float tile[32][33];
    int k0 = blockIdx.x * 32, n0 = blockIdx.y * 32;
    int tx = threadIdx.x, ty = threadIdx.y;  // 32 x 8
    for (int i = ty; i < 32; i += 8) {
        int k = k0 + i, np = n0 + tx;
        int part, j; unpack_col(np, part, j);
        tile[i][tx] = (k < kValid && j < Hh) ? src[(size_t)k*3000 + part*1000 + j] : 0.f;
    }
    __syncthreads();
    for (int i = ty; i < 32; i += 8) {
        int np = n0 + i, k = k0 + tx;
        dst[(size_t)np*dstLd + k] = f2bf(tile[tx][i]);
    }
}

__global__ void pack_biases(const float* __restrict__ b_hh, const float* __restrict__ b_ih,
                            const float* __restrict__ b_pred, const float* __restrict__ b_eos,
                            const float* __restrict__ W_eos,
                            float* __restrict__ bhhp, float* __restrict__ bihp,
                            float* __restrict__ bias_pe, unsigned short* __restrict__ Whead) {
    int i = blockIdx.x*256 + threadIdx.x;
    if (i < NCP) {
        int part, j; unpack_col(i, part, j);
        bhhp[i] = (j < Hh) ? b_hh[part*1000 + j] : 0.f;
        bihp[i] = (j < Hh) ? b_ih[part*1000 + j] : 0.f;
    }
    if (i < 256) bias_pe[i] = (i < 247) ? b_pred[i] : (i == 247 ? b_eos[0] : 0.f);
    if (i < KP_G) Whead[(size_t)247*KP_G + i] = f2bf(i < Hh ? W_eos[i] : 0.f);  // eos row
}

__global__ void cvt_h0(const float* __restrict__ h0, unsigned short* __restrict__ h0b,
                       float* __restrict__ h0f) {
    int i = blockIdx.x*256 + threadIdx.x;  // 256*1024
    int b = i >> 10, j = i & 1023;
    float v = (j < Hh) ? h0[(size_t)b*Hh + j] : 0.f;
    h0b[i] = f2bf(v);
    h0f[i] = v;
}

// ================= bf16 MFMA GEMM: C = act(A) @ B^T + bias ===================
// Bt[n][k], k padded to KTOT. AMODE 0: A bf16 [M][KTOT]. AMODE 1: A fp32 [M][1000] selu.
// AMODE 2: A bf16 [M][KTOT], selu.
template<int AMODE, int KTOT>
__launch_bounds__(256)
__global__ void gemm_bf16(const void* __restrict__ Aptr, const unsigned short* __restrict__ Bt,
                          const float* __restrict__ bias, float* __restrict__ C, int ldc) {
    constexpr int BM = 64, BN = 128, BK = 64, KP = 72;
    __shared__ unsigned short As[BM * KP];
    __shared__ unsigned short Bs[BN * KP];
    int tid = threadIdx.x;
    int m0 = blockIdx.y * BM, n0 = blockIdx.x * BN;
    int lane = tid & 63, wid = tid >> 6;
    int wm = wid >> 1, wn = wid & 1;
    f32x4 acc[2][4];
    #pragma unroll
    for (int i = 0; i < 2; i++)
        #pragma unroll
        for (int j = 0; j < 4; j++) acc[i][j] = (f32x4){0.f, 0.f, 0.f, 0.f};

    for (int k0 = 0; k0 < KTOT; k0 += BK) {
        #pragma unroll
        for (int e = 0; e < 2; ++e) {
            int idx = tid + e*256;
            int row = idx >> 3, kc = idx & 7;
            int k = k0 + kc*8;
            int rg = m0 + row;
            bf16x8 v;
            if (AMODE == 1) {
                if (k < Hh) {
                    const float4* p = (const float4*)((const float*)Aptr + (size_t)rg*Hh + k);
                    float4 x = p[0], y = p[1];
                    v[0]=(short)f2bf(selu_f(x.x)); v[1]=(short)f2bf(selu_f(x.y));
                    v[2]=(short)f2bf(selu_f(x.z)); v[3]=(short)f2bf(selu_f(x.w));
                    v[4]=(short)f2bf(selu_f(y.x)); v[5]=(short)f2bf(selu_f(y.y));
                    v[6]=(short)f2bf(selu_f(y.z)); v[7]=(short)f2bf(selu_f(y.w));
                } else {
                    #pragma unroll
                    for (int j = 0; j < 8; j++) v[j] = 0;
                }
            } else {
                v = *(const bf16x8*)((const unsigned short*)Aptr + (size_t)rg*KTOT + k);
                if (AMODE == 2) {
                    #pragma unroll
                    for (int j = 0; j < 8; j++)
                        v[j] = (short)f2bf(selu_f(bf2f((unsigned short)v[j])));
                }
            }
            *(bf16x8*)(&As[row*KP + kc*8]) = v;
        }
        #pragma unroll
        for (int e = 0; e < 4; ++e) {
            int idx = tid + e*256;
            int row = idx >> 3, kc = idx & 7;
            bf16x8 v = *(const bf16x8*)(Bt + (size_t)(n0 + row)*KTOT + k0 + kc*8);
            *(bf16x8*)(&Bs[row*KP + kc*8]) = v;
        }
        __syncthreads();
        #pragma unroll
        for (int kk = 0; kk < 2; ++kk) {
            bf16x8 af[2], bfr[4];
            #pragma unroll
            for (int mi = 0; mi < 2; mi++)
                af[mi] = *(const bf16x8*)(&As[(wm*32 + mi*16 + (lane & 15))*KP + kk*32 + (lane >> 4)*8]);
            #pragma unroll
            for (int ni = 0; ni < 4; ni++)
                bfr[ni] = *(const bf16x8*)(&Bs[(wn*64 + ni*16 + (lane & 15))*KP + kk*32 + (lane >> 4)*8]);
            #pragma unroll
            for (int mi = 0; mi < 2; mi++)
                #pragma unroll
                for (int ni = 0; ni < 4; ni++)
                    acc[mi][ni] = __builtin_amdgcn_mfma_f32_16x16x32_bf16(af[mi], bfr[ni], acc[mi][ni], 0, 0, 0);
        }
        __syncthreads();
    }
    int cr = (lane >> 4) * 4, cc = lane & 15;
    #pragma unroll
    for (int mi = 0; mi < 2; mi++) {
        #pragma unroll
        for (int ni = 0; ni < 4; ni++) {
            int col = n0 + wn*64 + ni*16 + cc;
            float bv = bias ? bias[col] : 0.f;
            #pragma unroll
            for (int r = 0; r < 4; r++) {
                int row = m0 + wm*32 + mi*16 + cr + r;
                C[(size_t)row*ldc + col] = acc[mi][ni][r] + bv;
            }
        }
    }
}

// ================= fused GRU step: h@Whh (packed) + gates in epilogue ========
// grid (32, 8): n-tiles of 96 (2 gate-groups), m-tiles of 32. 4 waves: wm x wn.
__launch_bounds__(256)
__global__ void gru_step(const unsigned short* __restrict__ hbA, const unsigned short* __restrict__ Wp,
                         const float* __restrict__ bhhp, const float* __restrict__ gi,
                         const float* __restrict__ hprevf, float* __restrict__ hnextf,
                         unsigned short* __restrict__ hb_out) {
    constexpr int BK = 64, KP = 72;
    __shared__ unsigned short As[32 * KP];
    __shared__ unsigned short Bs[96 * KP];
    int tid = threadIdx.x, lane = tid & 63, wid = tid >> 6;
    int wm = wid >> 1, wn = wid & 1;
    int n0 = blockIdx.x * 96, m0 = blockIdx.y * 32;
    f32x4 acc[3];
    #pragma unroll
    for (int f = 0; f < 3; f++) acc[f] = (f32x4){0.f,0.f,0.f,0.f};

    for (int k0 = 0; k0 < KP_G; k0 += BK) {
        {   // stage A: 32 rows x 64 k = 256 chunks of 8
            int row = tid >> 3, kc = tid & 7;
            *(bf16x8*)(&As[row*KP + kc*8]) =
                *(const bf16x8*)(hbA + (size_t)(m0 + row)*KP_G + k0 + kc*8);
        }
        #pragma unroll
        for (int e = 0; e < 3; ++e) {   // stage B: 96 x 64 = 768 chunks
            int idx = tid + e*256;
            int row = idx >> 3, kc = idx & 7;
            *(bf16x8*)(&Bs[row*KP + kc*8]) =
                *(const bf16x8*)(Wp + (size_t)(n0 + row)*KP_G + k0 + kc*8);
        }
        __syncthreads();
        #pragma unroll
        for (int kk = 0; kk < 2; ++kk) {
            bf16x8 af = *(const bf16x8*)(&As[(wm*16 + (lane & 15))*KP + kk*32 + (lane >> 4)*8]);
            #pragma unroll
            for (int f = 0; f < 3; f++) {
                bf16x8 bf = *(const bf16x8*)(&Bs[(wn*48 + f*16 + (lane & 15))*KP + kk*32 + (lane >> 4)*8]);
                acc[f] = __builtin_amdgcn_mfma_f32_16x16x32_bf16(af, bf, acc[f], 0, 0, 0);
            }
        }
        __syncthreads();
    }
    // epilogue: gates. lane holds r/z/n for j = g*16 + c, rows (lane>>4)*4 + r.
    int c = lane & 15, r0 = (lane >> 4) * 4;
    int g = n0 / 48 + wn;
    int j = g * 16 + c;
    float br = bhhp[g*48 + c], bz = bhhp[g*48 + 16 + c], bn_ = bhhp[g*48 + 32 + c];
    #pragma unroll
    for (int r = 0; r < 4; r++) {
        int row = m0 + wm*16 + r0 + r;
        const float* girow = gi + (size_t)row*NCP + g*48;
        float gh_r = acc[0][r] + br;
        float gh_z = acc[1][r] + bz;
        float gh_n = acc[2][r] + bn_;
        float rr = 1.f/(1.f + __expf(-(girow[c] + gh_r)));
        float zz = 1.f/(1.f + __expf(-(girow[16 + c] + gh_z)));
        float nn = tanhf(girow[32 + c] + rr * gh_n);
        float hp = hprevf[(size_t)row*KP_G + j];
        float h = (1.f - zz)*nn + zz*hp;
        hnextf[(size_t)row*KP_G + j] = h;
        hb_out[(size_t)row*KP_G + j] = f2bf(h);
    }
}

// ================= per-(t,b) outputs ========================================
__global__ void output_kernel(const float* __restrict__ pe, const float* __restrict__ fu,
                              const float* __restrict__ encf, const float* __restrict__ b_fuse,
                              const float* __restrict__ W_copy, const float* __restrict__ b_copy,
                              float* __restrict__ out) {
    __shared__ float sf[100];
    __shared__ float swc[100];
    __shared__ float scp[101];
    __shared__ float spred[248];
    __shared__ float sred[256];
    int row = blockIdx.x;               // t*256 + b
    int b = row & 255;
    int tid = threadIdx.x, lane = tid & 63, wave = tid >> 6;
    if (tid < 100) { sf[tid] = fu[(size_t)row*128 + tid] + b_fuse[tid]; swc[tid] = W_copy[tid]; }
    if (tid < 248) spred[tid] = pe[(size_t)row*256 + tid];
    __syncthreads();
    if (tid == 0) scp[100] = spred[247];
    const float* efb = encf + (size_t)b*Ll*128;
    for (int l = wave; l < Ll; l += 4) {
        const float* ef = efb + (size_t)l*128;
        float p = selu_f(sf[lane] + ef[lane]) * swc[lane];
        if (lane < 36) p += selu_f(sf[lane+64] + ef[lane+64]) * swc[lane+64];
        for (int off = 32; off > 0; off >>= 1) p += __shfl_down(p, off);
        if (lane == 0) scp[l] = p + b_copy[0];
    }
    __syncthreads();
    float* ob = out + (size_t)row*OUTW;
    float m = (tid < 248) ? spred[tid] : -1e30f;
    sred[tid] = m; __syncthreads();
    for (int s = 128; s > 0; s >>= 1) { if (tid < s) sred[tid] = fmaxf(sred[tid], sred[tid+s]); __syncthreads(); }
    m = sred[0]; __syncthreads();
    float ps = (tid < 248) ? expf(spred[tid] - m) : 0.f;
    sred[tid] = ps; __syncthreads();
    for (int s = 128; s > 0; s >>= 1) { if (tid < s) sred[tid] += sred[tid+s]; __syncthreads(); }
    float lse = m + logf(sred[0]);
    __syncthreads();
    if (tid < 248) ob[tid] = spred[tid] - lse;
    m = (tid < 101) ? scp[tid] : -1e30f;
    sred[tid] = m; __syncthreads();
    for (int s = 128; s > 0; s >>= 1) { if (tid < s) sred[tid] = fmaxf(sred[tid], sred[tid+s]); __syncthreads(); }
    m = sred[0]; __syncthreads();
    ps = (tid < 101) ? expf(scp[tid] - m) : 0.f;
    sred[tid] = ps; __syncthreads();
    for (int s = 128; s > 0; s >>= 1) { if (tid < s) sred[tid] += sred[tid+s]; __syncthreads(); }
    lse = m + logf(sred[0]);
    __syncthreads();
    if (tid < 101) ob[248 + tid] = scp[tid] - lse;
}

// ============================================================================
extern "C" void kernel_launch(void* const* d_in, const int* in_sizes, int n_in,
                              void* d_out, int out_size, void* d_ws, size_t ws_size,
                              hipStream_t stream) {
    const float* emb    = (const float*)d_in[0];
    const float* enc    = (const float*)d_in[1];
    const float* conv   = (const float*)d_in[2];
    const float* h0     = (const float*)d_in[3];
    const float* W_attn = (const float*)d_in[4];
    const float* W_comb = (const float*)d_in[6];
    const float* b_comb = (const float*)d_in[7];
    const float* W_ih   = (const float*)d_in[8];
    const float* W_hh   = (const float*)d_in[9];
    const float* b_ih   = (const float*)d_in[10];
    const float* b_hh   = (const float*)d_in[11];
    const float* W_eos  = (const float*)d_in[12];
    const float* b_eos  = (const float*)d_in[13];
    const float* W_pred = (const float*)d_in[14];
    const float* b_pred = (const float*)d_in[15];
    const float* W_fuse = (const float*)d_in[16];
    const float* b_fuse = (const float*)d_in[17];
    const float* W_copy = (const float*)d_in[18];
    const float* b_copy = (const float*)d_in[19];
    float* out = (float*)d_out;

    char* p = (char*)d_ws;
    auto alloc = [&](size_t bytes) -> void* {
        void* r = (void*)p; p += (bytes + 255) & ~(size_t)255; return r;
    };
    float* pm_enc   = (float*)alloc((size_t)Bb*2*2*4);
    float* pm_conv  = (float*)alloc((size_t)Bb*4*2*4);
    float* pc_enc   = (float*)alloc((size_t)Bb*2*1000*4);
    float* pc_conv  = (float*)alloc((size_t)Bb*4*1000*4);
    float* c_buf  = (float*)alloc((size_t)Bb*Hh*4);
    float* rc_buf = (float*)alloc((size_t)Bb*Hh*4);
    float* xc     = (float*)alloc((size_t)Bb*Ee*4);
    float* xrc    = (float*)alloc((size_t)Bb*Ee*4);
    unsigned short* x_allb = (unsigned short*)alloc((size_t)Tt*Bb*KP_E*2);
    float* gi_all = (float*)alloc((size_t)Tt*Bb*NCP*4);
    float* encf   = (float*)alloc((size_t)Bb*Ll*128*4);
    unsigned short* Wp    = (unsigned short*)alloc((size_t)NCP*KP_G*2);
    unsigned short* Wihpb = (unsigned short*)alloc((size_t)NCP*KP_E*2);
    unsigned short* Whead = (unsigned short*)alloc((size_t)256*KP_G*2);
    unsigned short* Wft   = (unsigned short*)alloc((size_t)128*KP_G*2);
    unsigned short* Wfb   = (unsigned short*)alloc((size_t)128*KP_G*2);
    float* bhhp    = (float*)alloc(NCP*4);
    float* bihp    = (float*)alloc(NCP*4);
    float* bias_pe = (float*)alloc(256*4);
    float* h_f[2];
    h_f[0] = (float*)alloc((size_t)Bb*KP_G*4);
    h_f[1] = (float*)alloc((size_t)Bb*KP_G*4);
    float* h0f = (float*)alloc((size_t)Bb*KP_G*4);
    unsigned short* h0b    = (unsigned short*)alloc((size_t)Bb*KP_G*2);
    unsigned short* hb_all = (unsigned short*)alloc((size_t)Tt*Bb*KP_G*2);
    float* pe = (float*)alloc((size_t)Tt*Bb*256*4);
    float* fu = (float*)alloc((size_t)Tt*Bb*128*4);

    // ---- attention (time-invariant; one pass, online softmax) ----
    attn_online<<<dim3(Bb, 2), 256, 0, stream>>>(enc,  W_attn + Hh, Ll, 50, pm_enc,  pc_enc,  2);
    attn_online<<<dim3(Bb, 4), 256, 0, stream>>>(conv, W_attn + Hh, Rr, 62, pm_conv, pc_conv, 4);
    attn_combine<<<Bb, 256, 0, stream>>>(pm_enc,  pc_enc,  c_buf,  2);
    attn_combine<<<Bb, 256, 0, stream>>>(pm_conv, pc_conv, rc_buf, 4);
    xcxrc_kernel<<<Bb, 128, 0, stream>>>(c_buf, rc_buf, W_comb, b_comb, xc, xrc);
    xall_kernel<<<Bb*Tt, 128, 0, stream>>>(emb, W_comb, xc, xrc, x_allb);

    // ---- weight packing ----
    pack_gates_T<<<dim3(32, 96), dim3(32, 8), 0, stream>>>(W_hh, Hh, Wp,    KP_G);
    pack_gates_T<<<dim3(4,  96), dim3(32, 8), 0, stream>>>(W_ih, Ee, Wihpb, KP_E);
    transpose_cvt<<<dim3(32, 8), dim3(32, 8), 0, stream>>>(W_pred, 247, Hh, 247, 0, Whead, 256);
    transpose_cvt_fuse<<<dim3(32, 4, 2), dim3(32, 8), 0, stream>>>(W_fuse, Wft, Wfb);
    pack_biases<<<12, 256, 0, stream>>>(b_hh, b_ih, b_pred, b_eos, W_eos, bhhp, bihp, bias_pe, Whead);
    cvt_h0<<<Bb*KP_G/256, 256, 0, stream>>>(h0, h0b, h0f);

    // ---- batched precompute GEMMs ----
    gemm_bf16<0,KP_E><<<dim3(NCP/128, Tt*Bb/64), 256, 0, stream>>>(x_allb, Wihpb, bihp, gi_all, NCP);
    gemm_bf16<1,KP_G><<<dim3(1, (Bb*Ll)/64), 256, 0, stream>>>(enc, Wfb, nullptr, encf, 128);

    // ---- serial GRU: one fused kernel per step (launch gaps < fence cost) ----
    const unsigned short* hbprev = h0b;
    const float* hprev = h0f;
    for (int t = 0; t < Tt; ++t) {
        float* hnext = h_f[t & 1];
        unsigned short* hbnext = hb_all + (size_t)t*Bb*KP_G;
        gru_step<<<dim3(32, 8), 256, 0, stream>>>(hbprev, Wp, bhhp,
                                                  gi_all + (size_t)t*Bb*NCP,
                                                  hprev, hnext, hbnext);
        hbprev = hbnext; hprev = hnext;
    }

    // ---- batched heads over all (t,b) ----
    gemm_bf16<0,KP_G><<<dim3(2, Tt*Bb/64), 256, 0, stream>>>(hb_all, Whead, bias_pe, pe, 256);
    gemm_bf16<2,KP_G><<<dim3(1, Tt*Bb/64), 256, 0, stream>>>(hb_all, Wft, nullptr, fu, 128);
    output_kernel<<<Tt*Bb, 256, 0, stream>>>(pe, fu, encf, b_fuse, W_copy, b_copy, out);
}

// Round 6
// 512.374 us; speedup vs baseline: 2.0969x; 1.0498x over previous
//
#include <hip/hip_runtime.h>
#include <hip/hip_bf16.h>
#include <math.h>

#define SELU_ALPHA 1.6732632423543772f
#define SELU_SCALE 1.0507009873554805f

typedef __attribute__((ext_vector_type(8))) short bf16x8;
typedef __attribute__((ext_vector_type(4))) float f32x4;

__device__ __forceinline__ float selu_f(float x) {
    return x > 0.f ? SELU_SCALE * x : SELU_SCALE * SELU_ALPHA * (__expf(x) - 1.f);
}
__device__ __forceinline__ unsigned short f2bf(float f) {
    __hip_bfloat16 h = __float2bfloat16(f);
    return *(unsigned short*)&h;
}
__device__ __forceinline__ float bf2f(unsigned short u) {
    unsigned int x = ((unsigned int)u) << 16;
    float f; __builtin_memcpy(&f, &x, 4); return f;
}

constexpr int Bb = 256, Ll = 100, Hh = 1000, Ee = 100, Rr = 247, Tt = 15;
constexpr int KP_G = 1024;             // padded K for H-sized bf16 GEMMs
constexpr int KP_E = 128;              // padded K for E-sized (gi) GEMM
constexpr int NCP = 3072;              // packed gate cols: 64 groups x 48 (r16|z16|n16)
constexpr int OUTW = Rr + 1 + Ll + 1;  // 349

// map packed col n' -> (part, j).  g=n'/48, rem=n'%48, part=rem/16, c=rem%16, j=g*16+c
__device__ __forceinline__ void unpack_col(int np, int& part, int& j) {
    int g = np / 48, rem = np % 48;
    part = rem >> 4;
    j = g * 16 + (rem & 15);
}

// ================= one-pass online-softmax attention (4-row unrolled) =======
__global__ void attn_online(const float* __restrict__ mem, const float* __restrict__ Wb,
                            int Nmem, int chunk, float* __restrict__ part_ms,
                            float* __restrict__ part_ctx, int nch) {
    __shared__ float4 sWb[256];
    __shared__ float sred[2][4][4];   // [parity][wave][row]
    int b = blockIdx.x, ch = blockIdx.y;
    int tid = threadIdx.x, lane = tid & 63, wv = tid >> 6;
    sWb[tid] = (tid < 250) ? ((const float4*)Wb)[tid] : (float4){0.f,0.f,0.f,0.f};
    __syncthreads();
    int l0 = ch * chunk, l1 = min(Nmem, l0 + chunk);
    float m = -1e30f, ssum = 0.f;
    float4 ctx = {0.f,0.f,0.f,0.f};
    const float* base = mem + (size_t)b * Nmem * 1000;
    float4 w = sWb[tid];
    bool act = tid < 250;
    int par = 0;
    for (int l = l0; l < l1; l += 4, par ^= 1) {
        float4 v[4];
        float pv[4];
        #pragma unroll
        for (int i = 0; i < 4; i++) {
            bool valid = act && (l + i < l1);
            v[i] = valid ? *(const float4*)(base + (size_t)(l+i) * 1000 + tid * 4)
                         : (float4){0.f,0.f,0.f,0.f};
            pv[i] = v[i].x*w.x + v[i].y*w.y + v[i].z*w.z + v[i].w*w.w;
        }
        #pragma unroll
        for (int off = 32; off > 0; off >>= 1) {
            #pragma unroll
            for (int i = 0; i < 4; i++) pv[i] += __shfl_down(pv[i], off);
        }
        if (lane == 0) {
            #pragma unroll
            for (int i = 0; i < 4; i++) sred[par][wv][i] = pv[i];
        }
        __syncthreads();
        float s[4];
        #pragma unroll
        for (int i = 0; i < 4; i++)
            s[i] = (l + i < l1) ? (sred[par][0][i] + sred[par][1][i] +
                                   sred[par][2][i] + sred[par][3][i]) : -1e30f;
        float mn = fmaxf(fmaxf(fmaxf(s[0], s[1]), fmaxf(s[2], s[3])), m);
        float sc = __expf(m - mn);
        float wt[4];
        #pragma unroll
        for (int i = 0; i < 4; i++) wt[i] = __expf(s[i] - mn);
        ssum = ssum*sc + wt[0] + wt[1] + wt[2] + wt[3];
        ctx.x = ctx.x*sc + wt[0]*v[0].x + wt[1]*v[1].x + wt[2]*v[2].x + wt[3]*v[3].x;
        ctx.y = ctx.y*sc + wt[0]*v[0].y + wt[1]*v[1].y + wt[2]*v[2].y + wt[3]*v[3].y;
        ctx.z = ctx.z*sc + wt[0]*v[0].z + wt[1]*v[1].z + wt[2]*v[2].z + wt[3]*v[3].z;
        ctx.w = ctx.w*sc + wt[0]*v[0].w + wt[1]*v[1].w + wt[2]*v[2].w + wt[3]*v[3].w;
        m = mn;
    }
    int pidx = b * nch + ch;
    if (tid == 0) { part_ms[pidx*2] = m; part_ms[pidx*2 + 1] = ssum; }
    if (act) *(float4*)(part_ctx + (size_t)pidx * 1000 + tid * 4) = ctx;
}

// merged combine: blocks 0..255 -> enc (nch 4), 256..511 -> conv (nch 8)
__global__ void attn_combine2(const float* __restrict__ pm_enc, const float* __restrict__ pc_enc,
                              float* __restrict__ c_buf,
                              const float* __restrict__ pm_conv, const float* __restrict__ pc_conv,
                              float* __restrict__ rc_buf) {
    __shared__ float sm[8], ss[8];
    int bb = blockIdx.x, tid = threadIdx.x;
    const float* pm; const float* pc; float* outp; int nch, b;
    if (bb < 256) { b = bb;       pm = pm_enc;  pc = pc_enc;  outp = c_buf;  nch = 4; }
    else          { b = bb - 256; pm = pm_conv; pc = pc_conv; outp = rc_buf; nch = 8; }
    if (tid < nch) { sm[tid] = pm[(b*nch + tid)*2]; ss[tid] = pm[(b*nch + tid)*2 + 1]; }
    __syncthreads();
    float M = -1e30f;
    for (int c = 0; c < nch; ++c) M = fmaxf(M, sm[c]);
    float tot = 0.f;
    for (int c = 0; c < nch; ++c) tot += ss[c] * __expf(sm[c] - M);
    float inv = 1.f / tot;
    if (tid < 250) {
        float4 acc = {0,0,0,0};
        for (int c = 0; c < nch; ++c) {
            float wgt = __expf(sm[c] - M) * inv;
            float4 v = *(const float4*)(pc + (size_t)(b*nch + c)*1000 + tid*4);
            acc.x += wgt*v.x; acc.y += wgt*v.y; acc.z += wgt*v.z; acc.w += wgt*v.w;
        }
        *(float4*)(outp + (size_t)b*1000 + tid*4) = acc;
    }
}

// ================= small precompute kernels =================================
__global__ void xcxrc_kernel(const float* __restrict__ c, const float* __restrict__ rc,
                             const float* __restrict__ W_comb, const float* __restrict__ b_comb,
                             float* __restrict__ xc, float* __restrict__ xrc) {
    __shared__ float sc[1000];
    __shared__ float sr[1000];
    int b = blockIdx.x, tid = threadIdx.x;  // 128 threads
    for (int k = tid; k < Hh; k += 128) { sc[k] = c[(size_t)b*Hh+k]; sr[k] = rc[(size_t)b*Hh+k]; }
    __syncthreads();
    if (tid < Ee) {
        float a0 = 0.f, a1 = 0.f;
        for (int k = 0; k < Hh; ++k) {
            float w = W_comb[(size_t)(Ee + k)*Ee + tid];
            a0 += sc[k]*w; a1 += sr[k]*w;
        }
        xc [(size_t)b*Ee + tid] = a0 + b_comb[tid];
        xrc[(size_t)b*Ee + tid] = a1 + b_comb[tid];
    }
}

// x_allb[t*256+b][128] (bf16) = emb@W_comb_top + (t%3?xc:xrc), zero-padded
__global__ void xall_kernel(const float* __restrict__ emb, const float* __restrict__ W_comb,
                            const float* __restrict__ xc, const float* __restrict__ xrc,
                            unsigned short* __restrict__ x_allb) {
    __shared__ float se[100];
    int bt = blockIdx.x; int b = bt / Tt, t = bt % Tt;
    int tid = threadIdx.x;  // 128
    if (tid < Ee) se[tid] = emb[(size_t)(b*Tt + t)*Ee + tid];
    __syncthreads();
    float v = 0.f;
    if (tid < Ee) {
        float a = 0.f;
        for (int k = 0; k < Ee; ++k) a += se[k] * W_comb[(size_t)k*Ee + tid];
        const float* xs = (t % 3 == 0) ? xrc : xc;
        v = a + xs[(size_t)b*Ee + tid];
    }
    x_allb[((size_t)t*Bb + b)*KP_E + tid] = f2bf(v);
}

// transpose+convert: dst[n][k] (ld 1024) = bf16(src[(row0+k)*srcLd + n]), zero-padded
__global__ void transpose_cvt(const float* __restrict__ src, int srcLd, int kValid, int nValid,
                              int row0, unsigned short* __restrict__ dst, int nRows) {
    __shared__ float tile[32][33];
    int k0 = blockIdx.x * 32, n0 = blockIdx.y * 32;
    int tx = threadIdx.x, ty = threadIdx.y;  // 32 x 8
    for (int i = ty; i < 32; i += 8) {
        int k = k0 + i, n = n0 + tx;
        tile[i][tx] = (k < kValid && n < nValid) ? src[(size_t)(row0 + k)*srcLd + n] : 0.f;
    }
    __syncthreads();
    for (int i = ty; i < 32; i += 8) {
        int n = n0 + i, k = k0 + tx;
        if (n < nRows) dst[(size_t)n*KP_G + k] = f2bf(tile[tx][i]);
    }
}

// W_fuse top/bot halves in one launch (z=0 -> rows 0..999 -> Wft; z=1 -> 1000.. -> Wfb)
__global__ void transpose_cvt_fuse(const float* __restrict__ W_fuse,
                                   unsigned short* __restrict__ Wft,
                                   unsigned short* __restrict__ Wfb) {
    __shared__ float tile[32][33];
    int k0 = blockIdx.x * 32, n0 = blockIdx.y * 32;
    int row0 = blockIdx.z ? 1000 : 0;
    unsigned short* dst = blockIdx.z ? Wfb : Wft;
    int tx = threadIdx.x, ty = threadIdx.y;  // 32 x 8
    for (int i = ty; i < 32; i += 8) {
        int k = k0 + i, n = n0 + tx;
        tile[i][tx] = (k < Hh && n < 100) ? W_fuse[(size_t)(row0 + k)*100 + n] : 0.f;
    }
    __syncthreads();
    for (int i = ty; i < 32; i += 8) {
        int n = n0 + i, k = k0 + tx;
        dst[(size_t)n*KP_G + k] = f2bf(tile[tx][i]);
    }
}

// packed-gate transpose: dst[np][k] (ld dstLd) = bf16(src[k][part*1000+j]); src [kValid][3000]
__global__ void pack_gates_T(const float* __restrict__ src, int kValid,
                             unsigned short* __restrict__ dst, int dstLd) {
    __shared__ float tile[32][33];
    int k0 = blockIdx.x * 32, n0 = blockIdx.y * 32;
    int tx = threadIdx.x, ty = threadIdx.y;  // 32 x 8
    for (int i = ty; i < 32; i += 8) {
        int k = k0 + i, np = n0 + tx;
        int part, j; unpack_col(np, part, j);
        tile[i][tx] = (k < kValid && j < Hh) ? src[(size_t)k*3000 + part*1000 + j] : 0.f;
    }
    __syncthreads();
    for (int i = ty; i < 32; i += 8) {
        int np = n0 + i, k = k0 + tx;
        dst[(size_t)np*dstLd + k] = f2bf(tile[tx][i]);
    }
}

__global__ void pack_biases(const float* __restrict__ b_hh, const float* __restrict__ b_ih,
                            const float* __restrict__ b_pred, const float* __restrict__ b_eos,
                            const float* __restrict__ W_eos,
                            float* __restrict__ bhhp, float* __restrict__ bihp,
                            float* __restrict__ bias_pe, unsigned short* __restrict__ Whead) {
    int i = blockIdx.x*256 + threadIdx.x;
    if (i < NCP) {
        int part, j; unpack_col(i, part, j);
        bhhp[i] = (j < Hh) ? b_hh[part*1000 + j] : 0.f;
        bihp[i] = (j < Hh) ? b_ih[part*1000 + j] : 0.f;
    }
    if (i < 256) bias_pe[i] = (i < 247) ? b_pred[i] : (i == 247 ? b_eos[0] : 0.f);
    if (i < KP_G) Whead[(size_t)247*KP_G + i] = f2bf(i < Hh ? W_eos[i] : 0.f);  // eos row
}

__global__ void cvt_h0(const float* __restrict__ h0, unsigned short* __restrict__ h0b,
                       float* __restrict__ h0f) {
    int i = blockIdx.x*256 + threadIdx.x;  // 256*1024
    int b = i >> 10, j = i & 1023;
    float v = (j < Hh) ? h0[(size_t)b*Hh + j] : 0.f;
    h0b[i] = f2bf(v);
    h0f[i] = v;
}

// ================= bf16 MFMA GEMM: C = act(A) @ B^T + bias ===================
// Bt[n][k], k padded to KTOT. AMODE 0: A bf16 [M][KTOT]. AMODE 1: A fp32 [M][1000] selu.
// AMODE 2: A bf16 [M][KTOT], selu.
template<int AMODE, int KTOT>
__launch_bounds__(256)
__global__ void gemm_bf16(const void* __restrict__ Aptr, const unsigned short* __restrict__ Bt,
                          const float* __restrict__ bias, float* __restrict__ C, int ldc) {
    constexpr int BM = 64, BN = 128, BK = 64, KP = 72;
    __shared__ unsigned short As[BM * KP];
    __shared__ unsigned short Bs[BN * KP];
    int tid = threadIdx.x;
    int m0 = blockIdx.y * BM, n0 = blockIdx.x * BN;
    int lane = tid & 63, wid = tid >> 6;
    int wm = wid >> 1, wn = wid & 1;
    f32x4 acc[2][4];
    #pragma unroll
    for (int i = 0; i < 2; i++)
        #pragma unroll
        for (int j = 0; j < 4; j++) acc[i][j] = (f32x4){0.f, 0.f, 0.f, 0.f};

    for (int k0 = 0; k0 < KTOT; k0 += BK) {
        #pragma unroll
        for (int e = 0; e < 2; ++e) {
            int idx = tid + e*256;
            int row = idx >> 3, kc = idx & 7;
            int k = k0 + kc*8;
            int rg = m0 + row;
            bf16x8 v;
            if (AMODE == 1) {
                if (k < Hh) {
                    const float4* p = (const float4*)((const float*)Aptr + (size_t)rg*Hh + k);
                    float4 x = p[0], y = p[1];
                    v[0]=(short)f2bf(selu_f(x.x)); v[1]=(short)f2bf(selu_f(x.y));
                    v[2]=(short)f2bf(selu_f(x.z)); v[3]=(short)f2bf(selu_f(x.w));
                    v[4]=(short)f2bf(selu_f(y.x)); v[5]=(short)f2bf(selu_f(y.y));
                    v[6]=(short)f2bf(selu_f(y.z)); v[7]=(short)f2bf(selu_f(y.w));
                } else {
                    #pragma unroll
                    for (int j = 0; j < 8; j++) v[j] = 0;
                }
            } else {
                v = *(const bf16x8*)((const unsigned short*)Aptr + (size_t)rg*KTOT + k);
                if (AMODE == 2) {
                    #pragma unroll
                    for (int j = 0; j < 8; j++)
                        v[j] = (short)f2bf(selu_f(bf2f((unsigned short)v[j])));
                }
            }
            *(bf16x8*)(&As[row*KP + kc*8]) = v;
        }
        #pragma unroll
        for (int e = 0; e < 4; ++e) {
            int idx = tid + e*256;
            int row = idx >> 3, kc = idx & 7;
            bf16x8 v = *(const bf16x8*)(Bt + (size_t)(n0 + row)*KTOT + k0 + kc*8);
            *(bf16x8*)(&Bs[row*KP + kc*8]) = v;
        }
        __syncthreads();
        #pragma unroll
        for (int kk = 0; kk < 2; ++kk) {
            bf16x8 af[2], bfr[4];
            #pragma unroll
            for (int mi = 0; mi < 2; mi++)
                af[mi] = *(const bf16x8*)(&As[(wm*32 + mi*16 + (lane & 15))*KP + kk*32 + (lane >> 4)*8]);
            #pragma unroll
            for (int ni = 0; ni < 4; ni++)
                bfr[ni] = *(const bf16x8*)(&Bs[(wn*64 + ni*16 + (lane & 15))*KP + kk*32 + (lane >> 4)*8]);
            #pragma unroll
            for (int mi = 0; mi < 2; mi++)
                #pragma unroll
                for (int ni = 0; ni < 4; ni++)
                    acc[mi][ni] = __builtin_amdgcn_mfma_f32_16x16x32_bf16(af[mi], bfr[ni], acc[mi][ni], 0, 0, 0);
        }
        __syncthreads();
    }
    int cr = (lane >> 4) * 4, cc = lane & 15;
    #pragma unroll
    for (int mi = 0; mi < 2; mi++) {
        #pragma unroll
        for (int ni = 0; ni < 4; ni++) {
            int col = n0 + wn*64 + ni*16 + cc;
            float bv = bias ? bias[col] : 0.f;
            #pragma unroll
            for (int r = 0; r < 4; r++) {
                int row = m0 + wm*32 + mi*16 + cr + r;
                C[(size_t)row*ldc + col] = acc[mi][ni][r] + bv;
            }
        }
    }
}

// ================= fused GRU step (double-buffered LDS) ======================
// grid (32, 8): n-tiles of 96 (2 gate-groups), m-tiles of 32. 4 waves.
__launch_bounds__(256)
__global__ void gru_step(const unsigned short* __restrict__ hbA, const unsigned short* __restrict__ Wp,
                         const float* __restrict__ bhhp, const float* __restrict__ gi,
                         const float* __restrict__ hprevf, float* __restrict__ hnextf,
                         unsigned short* __restrict__ hb_out) {
    constexpr int KP = 72;
    __shared__ unsigned short As[2][32 * KP];
    __shared__ unsigned short Bs[2][96 * KP];
    int tid = threadIdx.x, lane = tid & 63, wid = tid >> 6;
    int wm = wid >> 1, wn = wid & 1;
    int n0 = blockIdx.x * 96, m0 = blockIdx.y * 32;
    int sr = tid >> 3, skc = tid & 7;   // staging coords: 32 rows x 8 chunks
    const unsigned short* apA = hbA + (size_t)(m0 + sr)*KP_G + skc*8;
    const unsigned short* apB = Wp  + (size_t)(n0 + sr)*KP_G + skc*8;
    int sA = sr*KP + skc*8;
    int sB0 = sA, sB1 = (sr+32)*KP + skc*8, sB2 = (sr+64)*KP + skc*8;

    f32x4 acc[3];
    #pragma unroll
    for (int f = 0; f < 3; f++) acc[f] = (f32x4){0.f,0.f,0.f,0.f};

    // prologue: stage k-tile 0
    {
        bf16x8 ra  = *(const bf16x8*)apA;
        bf16x8 rb0 = *(const bf16x8*)apB;
        bf16x8 rb1 = *(const bf16x8*)(apB + (size_t)32*KP_G);
        bf16x8 rb2 = *(const bf16x8*)(apB + (size_t)64*KP_G);
        *(bf16x8*)&As[0][sA]  = ra;
        *(bf16x8*)&Bs[0][sB0] = rb0;
        *(bf16x8*)&Bs[0][sB1] = rb1;
        *(bf16x8*)&Bs[0][sB2] = rb2;
    }
    __syncthreads();

    int aoff  = (wm*16 + (lane & 15))*KP + (lane >> 4)*8;
    int boff0 = (wn*48 + (lane & 15))*KP + (lane >> 4)*8;
    int boff1 = boff0 + 16*KP;
    int boff2 = boff0 + 32*KP;

    int cur = 0;
    for (int k0 = 64; k0 < KP_G; k0 += 64) {
        // issue next tile's global loads (latency hides under MFMA below)
        bf16x8 ra  = *(const bf16x8*)(apA + k0);
        bf16x8 rb0 = *(const bf16x8*)(apB + k0);
        bf16x8 rb1 = *(const bf16x8*)(apB + (size_t)32*KP_G + k0);
        bf16x8 rb2 = *(const bf16x8*)(apB + (size_t)64*KP_G + k0);
        #pragma unroll
        for (int kk = 0; kk < 2; ++kk) {
            bf16x8 af = *(const bf16x8*)(&As[cur][aoff + kk*32]);
            acc[0] = __builtin_amdgcn_mfma_f32_16x16x32_bf16(af, *(const bf16x8*)(&Bs[cur][boff0 + kk*32]), acc[0], 0, 0, 0);
            acc[1] = __builtin_amdgcn_mfma_f32_16x16x32_bf16(af, *(const bf16x8*)(&Bs[cur][boff1 + kk*32]), acc[1], 0, 0, 0);
            acc[2] = __builtin_amdgcn_mfma_f32_16x16x32_bf16(af, *(const bf16x8*)(&Bs[cur][boff2 + kk*32]), acc[2], 0, 0, 0);
        }
        int nxt = cur ^ 1;
        *(bf16x8*)&As[nxt][sA]  = ra;
        *(bf16x8*)&Bs[nxt][sB0] = rb0;
        *(bf16x8*)&Bs[nxt][sB1] = rb1;
        *(bf16x8*)&Bs[nxt][sB2] = rb2;
        __syncthreads();
        cur = nxt;
    }
    // last k-tile
    #pragma unroll
    for (int kk = 0; kk < 2; ++kk) {
        bf16x8 af = *(const bf16x8*)(&As[cur][aoff + kk*32]);
        acc[0] = __builtin_amdgcn_mfma_f32_16x16x32_bf16(af, *(const bf16x8*)(&Bs[cur][boff0 + kk*32]), acc[0], 0, 0, 0);
        acc[1] = __builtin_amdgcn_mfma_f32_16x16x32_bf16(af, *(const bf16x8*)(&Bs[cur][boff1 + kk*32]), acc[1], 0, 0, 0);
        acc[2] = __builtin_amdgcn_mfma_f32_16x16x32_bf16(af, *(const bf16x8*)(&Bs[cur][boff2 + kk*32]), acc[2], 0, 0, 0);
    }

    // epilogue: gates. lane holds r/z/n for j = g*16 + c, rows (lane>>4)*4 + r.
    int c = lane & 15, r0 = (lane >> 4) * 4;
    int g = n0 / 48 + wn;
    int j = g * 16 + c;
    float br = bhhp[g*48 + c], bz = bhhp[g*48 + 16 + c], bn_ = bhhp[g*48 + 32 + c];
    #pragma unroll
    for (int r = 0; r < 4; r++) {
        int row = m0 + wm*16 + r0 + r;
        const float* girow = gi + (size_t)row*NCP + g*48;
        float rr = 1.f/(1.f + __expf(-(girow[c]      + acc[0][r] + br)));
        float zz = 1.f/(1.f + __expf(-(girow[16 + c] + acc[1][r] + bz)));
        float nn = tanhf(girow[32 + c] + rr * (acc[2][r] + bn_));
        float hp = hprevf[(size_t)row*KP_G + j];
        float h = (1.f - zz)*nn + zz*hp;
        hnextf[(size_t)row*KP_G + j] = h;
        hb_out[(size_t)row*KP_G + j] = f2bf(h);
    }
}

// ================= per-(t,b) outputs (shuffle-reduced log-softmax) ==========
__global__ void output_kernel(const float* __restrict__ pe, const float* __restrict__ fu,
                              const float* __restrict__ encf, const float* __restrict__ b_fuse,
                              const float* __restrict__ W_copy, const float* __restrict__ b_copy,
                              float* __restrict__ out) {
    __shared__ float sf[100];
    __shared__ float swc[100];
    __shared__ float scp[104];
    __shared__ float smx[4], ssx[4], smy[4], ssy[4];
    int row = blockIdx.x;               // t*256 + b
    int b = row & 255;
    int tid = threadIdx.x, lane = tid & 63, wv = tid >> 6;
    if (tid < 100) { sf[tid] = fu[(size_t)row*128 + tid] + b_fuse[tid]; swc[tid] = W_copy[tid]; }
    float x = (tid < 248) ? pe[(size_t)row*256 + tid] : -1e30f;
    if (tid == 247) scp[100] = x;       // eos into copy slot
    __syncthreads();                    // A: sf/swc ready
    const float* efb = encf + (size_t)b*Ll*128;
    for (int l = wv; l < Ll; l += 4) {
        const float* ef = efb + (size_t)l*128;
        float pp = selu_f(sf[lane] + ef[lane]) * swc[lane];
        if (lane < 36) pp += selu_f(sf[lane+64] + ef[lane+64]) * swc[lane+64];
        #pragma unroll
        for (int off = 32; off > 0; off >>= 1) pp += __shfl_down(pp, off);
        if (lane == 0) scp[l] = pp + b_copy[0];
    }
    float mx = x;
    #pragma unroll
    for (int off = 32; off > 0; off >>= 1) mx = fmaxf(mx, __shfl_xor(mx, off));
    if (lane == 0) smx[wv] = mx;
    __syncthreads();                    // B: scp + smx ready
    float m_x = fmaxf(fmaxf(smx[0], smx[1]), fmaxf(smx[2], smx[3]));
    float ex = (tid < 248) ? __expf(x - m_x) : 0.f;
    float sx = ex;
    #pragma unroll
    for (int off = 32; off > 0; off >>= 1) sx += __shfl_xor(sx, off);
    if (lane == 0) ssx[wv] = sx;
    float y = (tid < 101) ? scp[tid] : -1e30f;
    float my = y;
    #pragma unroll
    for (int off = 32; off > 0; off >>= 1) my = fmaxf(my, __shfl_xor(my, off));
    if (lane == 0) smy[wv] = my;
    __syncthreads();                    // C
    float* ob = out + (size_t)row*OUTW;
    float lse_x = m_x + __logf(ssx[0] + ssx[1] + ssx[2] + ssx[3]);
    if (tid < 248) ob[tid] = x - lse_x;
    float m_y = fmaxf(fmaxf(smy[0], smy[1]), fmaxf(smy[2], smy[3]));
    float ey = (tid < 101) ? __expf(y - m_y) : 0.f;
    float sy = ey;
    #pragma unroll
    for (int off = 32; off > 0; off >>= 1) sy += __shfl_xor(sy, off);
    if (lane == 0) ssy[wv] = sy;
    __syncthreads();                    // D
    float lse_y = m_y + __logf(ssy[0] + ssy[1] + ssy[2] + ssy[3]);
    if (tid < 101) ob[248 + tid] = y - lse_y;
}

// ============================================================================
extern "C" void kernel_launch(void* const* d_in, const int* in_sizes, int n_in,
                              void* d_out, int out_size, void* d_ws, size_t ws_size,
                              hipStream_t stream) {
    const float* emb    = (const float*)d_in[0];
    const float* enc    = (const float*)d_in[1];
    const float* conv   = (const float*)d_in[2];
    const float* h0     = (const float*)d_in[3];
    const float* W_attn = (const float*)d_in[4];
    const float* W_comb = (const float*)d_in[6];
    const float* b_comb = (const float*)d_in[7];
    const float* W_ih   = (const float*)d_in[8];
    const float* W_hh   = (const float*)d_in[9];
    const float* b_ih   = (const float*)d_in[10];
    const float* b_hh   = (const float*)d_in[11];
    const float* W_eos  = (const float*)d_in[12];
    const float* b_eos  = (const float*)d_in[13];
    const float* W_pred = (const float*)d_in[14];
    const float* b_pred = (const float*)d_in[15];
    const float* W_fuse = (const float*)d_in[16];
    const float* b_fuse = (const float*)d_in[17];
    const float* W_copy = (const float*)d_in[18];
    const float* b_copy = (const float*)d_in[19];
    float* out = (float*)d_out;

    char* p = (char*)d_ws;
    auto alloc = [&](size_t bytes) -> void* {
        void* r = (void*)p; p += (bytes + 255) & ~(size_t)255; return r;
    };
    float* pm_enc   = (float*)alloc((size_t)Bb*4*2*4);
    float* pm_conv  = (float*)alloc((size_t)Bb*8*2*4);
    float* pc_enc   = (float*)alloc((size_t)Bb*4*1000*4);
    float* pc_conv  = (float*)alloc((size_t)Bb*8*1000*4);
    float* c_buf  = (float*)alloc((size_t)Bb*Hh*4);
    float* rc_buf = (float*)alloc((size_t)Bb*Hh*4);
    float* xc     = (float*)alloc((size_t)Bb*Ee*4);
    float* xrc    = (float*)alloc((size_t)Bb*Ee*4);
    unsigned short* x_allb = (unsigned short*)alloc((size_t)Tt*Bb*KP_E*2);
    float* gi_all = (float*)alloc((size_t)Tt*Bb*NCP*4);
    float* encf   = (float*)alloc((size_t)Bb*Ll*128*4);
    unsigned short* Wp    = (unsigned short*)alloc((size_t)NCP*KP_G*2);
    unsigned short* Wihpb = (unsigned short*)alloc((size_t)NCP*KP_E*2);
    unsigned short* Whead = (unsigned short*)alloc((size_t)256*KP_G*2);
    unsigned short* Wft   = (unsigned short*)alloc((size_t)128*KP_G*2);
    unsigned short* Wfb   = (unsigned short*)alloc((size_t)128*KP_G*2);
    float* bhhp    = (float*)alloc(NCP*4);
    float* bihp    = (float*)alloc(NCP*4);
    float* bias_pe = (float*)alloc(256*4);
    float* h_f[2];
    h_f[0] = (float*)alloc((size_t)Bb*KP_G*4);
    h_f[1] = (float*)alloc((size_t)Bb*KP_G*4);
    float* h0f = (float*)alloc((size_t)Bb*KP_G*4);
    unsigned short* h0b    = (unsigned short*)alloc((size_t)Bb*KP_G*2);
    unsigned short* hb_all = (unsigned short*)alloc((size_t)Tt*Bb*KP_G*2);
    float* pe = (float*)alloc((size_t)Tt*Bb*256*4);
    float* fu = (float*)alloc((size_t)Tt*Bb*128*4);

    // ---- attention (time-invariant; one pass, online softmax) ----
    attn_online<<<dim3(Bb, 4), 256, 0, stream>>>(enc,  W_attn + Hh, Ll, 25, pm_enc,  pc_enc,  4);
    attn_online<<<dim3(Bb, 8), 256, 0, stream>>>(conv, W_attn + Hh, Rr, 31, pm_conv, pc_conv, 8);
    attn_combine2<<<512, 256, 0, stream>>>(pm_enc, pc_enc, c_buf, pm_conv, pc_conv, rc_buf);
    xcxrc_kernel<<<Bb, 128, 0, stream>>>(c_buf, rc_buf, W_comb, b_comb, xc, xrc);
    xall_kernel<<<Bb*Tt, 128, 0, stream>>>(emb, W_comb, xc, xrc, x_allb);

    // ---- weight packing ----
    pack_gates_T<<<dim3(32, 96), dim3(32, 8), 0, stream>>>(W_hh, Hh, Wp,    KP_G);
    pack_gates_T<<<dim3(4,  96), dim3(32, 8), 0, stream>>>(W_ih, Ee, Wihpb, KP_E);
    transpose_cvt<<<dim3(32, 8), dim3(32, 8), 0, stream>>>(W_pred, 247, Hh, 247, 0, Whead, 256);
    transpose_cvt_fuse<<<dim3(32, 4, 2), dim3(32, 8), 0, stream>>>(W_fuse, Wft, Wfb);
    pack_biases<<<12, 256, 0, stream>>>(b_hh, b_ih, b_pred, b_eos, W_eos, bhhp, bihp, bias_pe, Whead);
    cvt_h0<<<Bb*KP_G/256, 256, 0, stream>>>(h0, h0b, h0f);

    // ---- batched precompute GEMMs ----
    gemm_bf16<0,KP_E><<<dim3(NCP/128, Tt*Bb/64), 256, 0, stream>>>(x_allb, Wihpb, bihp, gi_all, NCP);
    gemm_bf16<1,KP_G><<<dim3(1, (Bb*Ll)/64), 256, 0, stream>>>(enc, Wfb, nullptr, encf, 128);

    // ---- serial GRU: one fused kernel per step ----
    const unsigned short* hbprev = h0b;
    const float* hprev = h0f;
    for (int t = 0; t < Tt; ++t) {
        float* hnext = h_f[t & 1];
        unsigned short* hbnext = hb_all + (size_t)t*Bb*KP_G;
        gru_step<<<dim3(32, 8), 256, 0, stream>>>(hbprev, Wp, bhhp,
                                                  gi_all + (size_t)t*Bb*NCP,
                                                  hprev, hnext, hbnext);
        hbprev = hbnext; hprev = hnext;
    }

    // ---- batched heads over all (t,b) ----
    gemm_bf16<0,KP_G><<<dim3(2, Tt*Bb/64), 256, 0, stream>>>(hb_all, Whead, bias_pe, pe, 256);
    gemm_bf16<2,KP_G><<<dim3(1, Tt*Bb/64), 256, 0, stream>>>(hb_all, Wft, nullptr, fu, 128);
    output_kernel<<<Tt*Bb, 256, 0, stream>>>(pe, fu, encf, b_fuse, W_copy, b_copy, out);
}